// Round 1
// baseline (89.323 us; speedup 1.0000x reference)
//
#include <hip/hip_runtime.h>

#define N 8192
#define BLOCK 256
#define JCHUNK 256
#define NIBLK (N / BLOCK)    // 32
#define NJBLK (N / JCHUNK)   // 32

// PE kernel: block (ib, jb) computes sum over i in ib-block, j in jb-chunk of
// sum_{9 shifts} 1/|r_i - r_j - s|, diagonal (i==j) fully masked (all 9 shifts),
// matching the JAX reference's eye-mask-per-shift semantics.
__global__ __launch_bounds__(BLOCK) void pe_kernel(const float* __restrict__ xy,
                                                   float* __restrict__ partial) {
    __shared__ float2 sj[JCHUNK];
    const int ib = blockIdx.x;
    const int jb = blockIdx.y;
    const int t  = threadIdx.x;
    const int i  = ib * BLOCK + t;

    const float xi = xy[2 * i];
    const float yi = xy[2 * i + 1];

    const int j0 = jb * JCHUNK;
    sj[t] = ((const float2*)xy)[j0 + t];   // one element per thread, coalesced
    __syncthreads();

    float acc = 0.0f;
#pragma unroll 4
    for (int jj = 0; jj < JCHUNK; ++jj) {
        float2 pj = sj[jj];                // LDS broadcast (conflict-free)
        float dx = xi - pj.x;
        float dy = yi - pj.y;
        const bool diag = (i == (j0 + jj));

        float dxm = dx + 10.0f, dxp = dx - 10.0f;
        float dym = dy + 10.0f, dyp = dy - 10.0f;
        float x0 = dx * dx,  xm = dxm * dxm, xp = dxp * dxp;
        float y0 = dy * dy,  ym = dym * dym, yp = dyp * dyp;

        // center term needs a safe d2 when diag (reference uses where(eye,1,d2))
        float d2c = diag ? 1.0f : (x0 + y0);

        float s = __builtin_amdgcn_rsqf(d2c)
                + __builtin_amdgcn_rsqf(x0 + ym)
                + __builtin_amdgcn_rsqf(x0 + yp)
                + __builtin_amdgcn_rsqf(xm + y0)
                + __builtin_amdgcn_rsqf(xm + ym)
                + __builtin_amdgcn_rsqf(xm + yp)
                + __builtin_amdgcn_rsqf(xp + y0)
                + __builtin_amdgcn_rsqf(xp + ym)
                + __builtin_amdgcn_rsqf(xp + yp);

        acc += diag ? 0.0f : s;
    }

    // deterministic block tree reduction
    __shared__ float red[BLOCK];
    red[t] = acc;
    __syncthreads();
    for (int s = BLOCK / 2; s > 0; s >>= 1) {
        if (t < s) red[t] += red[t + s];
        __syncthreads();
    }
    if (t == 0) partial[ib * NJBLK + jb] = red[0];
}

// Finisher: reduce the 1024 block partials + kinetic energy, write scalar.
__global__ __launch_bounds__(1024) void finish_kernel(const float* __restrict__ partial,
                                                      const float* __restrict__ pxy,
                                                      float* __restrict__ out) {
    const int t = threadIdx.x;
    float acc = partial[t];                     // exactly 1024 partials
    for (int k = t; k < 2 * N; k += 1024) {     // KE = sum p^2 / 2
        float p = pxy[k];
        acc += 0.5f * p * p;
    }
    __shared__ float red[1024];
    red[t] = acc;
    __syncthreads();
    for (int s = 512; s > 0; s >>= 1) {
        if (t < s) red[t] += red[t + s];
        __syncthreads();
    }
    if (t == 0) out[0] = red[0];
}

extern "C" void kernel_launch(void* const* d_in, const int* in_sizes, int n_in,
                              void* d_out, int out_size, void* d_ws, size_t ws_size,
                              hipStream_t stream) {
    const float* xy  = (const float*)d_in[0];
    const float* pxy = (const float*)d_in[1];
    float* out       = (float*)d_out;
    float* partial   = (float*)d_ws;   // needs 1024 floats = 4 KB

    dim3 grid(NIBLK, NJBLK);
    pe_kernel<<<grid, BLOCK, 0, stream>>>(xy, partial);
    finish_kernel<<<1, 1024, 0, stream>>>(partial, pxy, out);
}

// Round 2
// 55.382 us; speedup vs baseline: 1.6128x; 1.6128x over previous
//
#include <hip/hip_runtime.h>

#define N 8192
#define TILE 128
#define NB (N / TILE)              // 64 tiles per dim
#define NTRI (NB * (NB + 1) / 2)   // 2080 triangular tiles

// Triangular-tile PE kernel. Block b -> (ib, jb), ib <= jb.
// Diagonal tiles (ib==jb): full 128x128 with i==j masked (all 9 shifts), weight 1.
// Off-diagonal tiles: unmasked 128x128, weight 2 (i<->j symmetry of the 9-shift sum).
__global__ __launch_bounds__(TILE) void pe_kernel(const float* __restrict__ xy,
                                                  float* __restrict__ partial) {
    __shared__ float2 sj[TILE];
    const int t = threadIdx.x;

    // decode triangular index (scalar, <=64 iterations, once per block)
    int rem = blockIdx.x;
    int ib = 0;
    while (rem >= NB - ib) { rem -= NB - ib; ++ib; }
    const int jb = ib + rem;

    const int i = ib * TILE + t;
    const float xi = xy[2 * i];
    const float yi = xy[2 * i + 1];
    sj[t] = ((const float2*)xy)[jb * TILE + t];
    __syncthreads();

    float acc = 0.0f;

    if (ib == jb) {
        // diagonal tile: mask i==j (reference masks the diagonal for ALL 9 shifts)
#pragma unroll 8
        for (int jj = 0; jj < TILE; ++jj) {
            float2 pj = sj[jj];
            float dx = xi - pj.x;
            float dy = yi - pj.y;
            const bool diag = (t == jj);

            float dxm = dx + 10.0f, dxp = dx - 10.0f;
            float dym = dy + 10.0f, dyp = dy - 10.0f;
            float x0 = dx * dx,  xm = dxm * dxm, xp = dxp * dxp;
            float y0 = dy * dy,  ym = dym * dym, yp = dyp * dyp;

            float d2c = diag ? 1.0f : (x0 + y0);

            float s = __builtin_amdgcn_rsqf(d2c)
                    + __builtin_amdgcn_rsqf(x0 + ym)
                    + __builtin_amdgcn_rsqf(x0 + yp)
                    + __builtin_amdgcn_rsqf(xm + y0)
                    + __builtin_amdgcn_rsqf(xm + ym)
                    + __builtin_amdgcn_rsqf(xm + yp)
                    + __builtin_amdgcn_rsqf(xp + y0)
                    + __builtin_amdgcn_rsqf(xp + ym)
                    + __builtin_amdgcn_rsqf(xp + yp);

            acc += diag ? 0.0f : s;
        }
    } else {
        // off-diagonal tile: no diagonal possible, branch-free inner loop
#pragma unroll 8
        for (int jj = 0; jj < TILE; ++jj) {
            float2 pj = sj[jj];
            float dx = xi - pj.x;
            float dy = yi - pj.y;

            float dxm = dx + 10.0f, dxp = dx - 10.0f;
            float dym = dy + 10.0f, dyp = dy - 10.0f;
            float x0 = dx * dx,  xm = dxm * dxm, xp = dxp * dxp;
            float y0 = dy * dy,  ym = dym * dym, yp = dyp * dyp;

            float s = __builtin_amdgcn_rsqf(x0 + y0)
                    + __builtin_amdgcn_rsqf(x0 + ym)
                    + __builtin_amdgcn_rsqf(x0 + yp)
                    + __builtin_amdgcn_rsqf(xm + y0)
                    + __builtin_amdgcn_rsqf(xm + ym)
                    + __builtin_amdgcn_rsqf(xm + yp)
                    + __builtin_amdgcn_rsqf(xp + y0)
                    + __builtin_amdgcn_rsqf(xp + ym)
                    + __builtin_amdgcn_rsqf(xp + yp);

            acc += s;
        }
        acc += acc;   // weight 2 for the mirrored (j,i) tile
    }

    // deterministic block tree reduction
    __shared__ float red[TILE];
    red[t] = acc;
    __syncthreads();
    for (int s = TILE / 2; s > 0; s >>= 1) {
        if (t < s) red[t] += red[t + s];
        __syncthreads();
    }
    if (t == 0) partial[blockIdx.x] = red[0];
}

// Finisher: reduce NTRI block partials + kinetic energy, write scalar.
__global__ __launch_bounds__(1024) void finish_kernel(const float* __restrict__ partial,
                                                      const float* __restrict__ pxy,
                                                      float* __restrict__ out) {
    const int t = threadIdx.x;
    float acc = 0.0f;
    for (int k = t; k < NTRI; k += 1024) acc += partial[k];
    for (int k = t; k < 2 * N; k += 1024) {   // KE = sum p^2 / 2
        float p = pxy[k];
        acc += 0.5f * p * p;
    }
    __shared__ float red[1024];
    red[t] = acc;
    __syncthreads();
    for (int s = 512; s > 0; s >>= 1) {
        if (t < s) red[t] += red[t + s];
        __syncthreads();
    }
    if (t == 0) out[0] = red[0];
}

extern "C" void kernel_launch(void* const* d_in, const int* in_sizes, int n_in,
                              void* d_out, int out_size, void* d_ws, size_t ws_size,
                              hipStream_t stream) {
    const float* xy  = (const float*)d_in[0];
    const float* pxy = (const float*)d_in[1];
    float* out       = (float*)d_out;
    float* partial   = (float*)d_ws;   // NTRI floats = 8320 B

    pe_kernel<<<NTRI, TILE, 0, stream>>>(xy, partial);
    finish_kernel<<<1, 1024, 0, stream>>>(partial, pxy, out);
}

// Round 3
// 50.446 us; speedup vs baseline: 1.7707x; 1.0979x over previous
//
#include <hip/hip_runtime.h>

#define N 8192
#define TILE 128
#define NB (N / TILE)              // 64 tiles per dim
#define NTRI (NB * (NB + 1) / 2)   // 2080 triangular tiles
#define JSPLIT 2
#define JSUB (TILE / JSPLIT)       // 64 j-points per block

// Triangular-tile PE kernel, j-split for occupancy.
// Block (b, h): tile b -> (ib, jb) with ib <= jb, j-range [jb*TILE + h*JSUB, +JSUB).
// Diagonal tiles (ib==jb): i==j masked (all 9 shifts), weight 1.
// Off-diagonal tiles: unmasked, weight 2 (i<->j symmetry; shift set is self-negating).
__global__ __launch_bounds__(TILE) void pe_kernel(const float* __restrict__ xy,
                                                  float* __restrict__ partial) {
    __shared__ float2 sj[JSUB];
    const int t = threadIdx.x;

    // decode triangular index (scalar, <=64 cheap SALU iterations per block)
    int rem = blockIdx.x;
    int ib = 0;
    while (rem >= NB - ib) { rem -= NB - ib; ++ib; }
    const int jb = ib + rem;

    const int i = ib * TILE + t;
    const float2 pi = ((const float2*)xy)[i];
    const float xi = pi.x, yi = pi.y;

    const int j0 = jb * TILE + blockIdx.y * JSUB;
    if (t < JSUB) sj[t] = ((const float2*)xy)[j0 + t];
    __syncthreads();

    float acc = 0.0f;

    if (ib == jb) {
#pragma unroll 8
        for (int jj = 0; jj < JSUB; ++jj) {
            float2 pj = sj[jj];
            float dx = xi - pj.x;
            float dy = yi - pj.y;
            const bool diag = (i == (j0 + jj));

            float x0 = dx * dx, y0 = dy * dy;
            float tx = x0 + 100.0f, ty = y0 + 100.0f;
            float xm = fmaf(20.0f, dx, tx),  xp = fmaf(-20.0f, dx, tx);
            float ym = fmaf(20.0f, dy, ty),  yp = fmaf(-20.0f, dy, ty);

            float d2c = diag ? 1.0f : (x0 + y0);

            float s = __builtin_amdgcn_rsqf(d2c)
                    + __builtin_amdgcn_rsqf(x0 + ym)
                    + __builtin_amdgcn_rsqf(x0 + yp)
                    + __builtin_amdgcn_rsqf(xm + y0)
                    + __builtin_amdgcn_rsqf(xm + ym)
                    + __builtin_amdgcn_rsqf(xm + yp)
                    + __builtin_amdgcn_rsqf(xp + y0)
                    + __builtin_amdgcn_rsqf(xp + ym)
                    + __builtin_amdgcn_rsqf(xp + yp);

            acc += diag ? 0.0f : s;
        }
    } else {
#pragma unroll 8
        for (int jj = 0; jj < JSUB; ++jj) {
            float2 pj = sj[jj];
            float dx = xi - pj.x;
            float dy = yi - pj.y;

            float x0 = dx * dx, y0 = dy * dy;
            float tx = x0 + 100.0f, ty = y0 + 100.0f;
            float xm = fmaf(20.0f, dx, tx),  xp = fmaf(-20.0f, dx, tx);
            float ym = fmaf(20.0f, dy, ty),  yp = fmaf(-20.0f, dy, ty);

            float s = __builtin_amdgcn_rsqf(x0 + y0)
                    + __builtin_amdgcn_rsqf(x0 + ym)
                    + __builtin_amdgcn_rsqf(x0 + yp)
                    + __builtin_amdgcn_rsqf(xm + y0)
                    + __builtin_amdgcn_rsqf(xm + ym)
                    + __builtin_amdgcn_rsqf(xm + yp)
                    + __builtin_amdgcn_rsqf(xp + y0)
                    + __builtin_amdgcn_rsqf(xp + ym)
                    + __builtin_amdgcn_rsqf(xp + yp);

            acc += s;
        }
        acc += acc;   // weight 2 for the mirrored (j,i) tile
    }

    // deterministic block tree reduction
    __shared__ float red[TILE];
    red[t] = acc;
    __syncthreads();
    for (int s = TILE / 2; s > 0; s >>= 1) {
        if (t < s) red[t] += red[t + s];
        __syncthreads();
    }
    if (t == 0) partial[blockIdx.y * NTRI + blockIdx.x] = red[0];
}

// Finisher: reduce NTRI*JSPLIT block partials + kinetic energy, write scalar.
__global__ __launch_bounds__(1024) void finish_kernel(const float* __restrict__ partial,
                                                      const float* __restrict__ pxy,
                                                      float* __restrict__ out) {
    const int t = threadIdx.x;
    float acc = 0.0f;
    for (int k = t; k < NTRI * JSPLIT; k += 1024) acc += partial[k];
    for (int k = t; k < 2 * N; k += 1024) {   // KE = sum p^2 / 2
        float p = pxy[k];
        acc += 0.5f * p * p;
    }
    __shared__ float red[1024];
    red[t] = acc;
    __syncthreads();
    for (int s = 512; s > 0; s >>= 1) {
        if (t < s) red[t] += red[t + s];
        __syncthreads();
    }
    if (t == 0) out[0] = red[0];
}

extern "C" void kernel_launch(void* const* d_in, const int* in_sizes, int n_in,
                              void* d_out, int out_size, void* d_ws, size_t ws_size,
                              hipStream_t stream) {
    const float* xy  = (const float*)d_in[0];
    const float* pxy = (const float*)d_in[1];
    float* out       = (float*)d_out;
    float* partial   = (float*)d_ws;   // NTRI*JSPLIT floats = 16.6 KB

    dim3 grid(NTRI, JSPLIT);
    pe_kernel<<<grid, TILE, 0, stream>>>(xy, partial);
    finish_kernel<<<1, 1024, 0, stream>>>(partial, pxy, out);
}